// Round 1
// baseline (241.392 us; speedup 1.0000x reference)
//
#include <hip/hip_runtime.h>

// ---------------------------------------------------------------------------
// LinearDepthWiseAttention: out = w_out @ ((softmax(K) V^T)^T Q) + b_out
// Folded:  W2[c, h*64+d] = sum_e w_out[c,h*64+e] * ctx[h,d,e]
//          out[b]        = W2[b] @ q[b]  (+ b_out)
// Pipeline:
//   K0 cast_w        : w_qkv fp32 -> bf16                   (ws)
//   K1 transpose_cast: net (b,c,n) fp32 -> net_T (b,n,c) bf16  (scratch in d_out!)
//   K2 gemm_qkv      : qkv = w_qkv @ net_T^T ; q stored transposed (q_t[b][n][o]),
//                      k,v stored row-major [b][o][n], all bf16, MFMA 16x16x32
//   K3 ctx_kernel    : per (b,h): s_d = sum_n exp(k), ctx = (exp(k) @ v^T)/s
//                      (no max subtraction: |k| <= ~6, fp32-safe)
//   K4 fold_w2       : W2 = w_out (x) ctx  -> bf16
//   K5 gemm_out      : out = W2 @ q_t^T + b_out  (fp32 out)
// Workspace layout (bytes):
//   q_t   [16][4096][512] bf16 @ 0          (67108864)
//   kbuf  [16][512][4096] bf16 @ 67108864   (67108864)
//   vbuf  [16][512][4096] bf16 @ 134217728  (67108864)
//   ctx   [128][64][64]   f32  @ 201326592  (2097152)
//   W2    [16][256][512]  bf16 @ 203423744  (4194304)
//   wqb   [1536][256]     bf16 @ 207618048  (786432)   total ~208.4 MB
//   net_T lives in d_out (33.5MB of 67MB), dead before gemm_out overwrites.
// ---------------------------------------------------------------------------

typedef unsigned short u16;
typedef unsigned int u32;
typedef __attribute__((ext_vector_type(4))) u16 u16x4;
typedef __attribute__((ext_vector_type(4))) u32 u32x4;
typedef __attribute__((ext_vector_type(4))) float f32x4;
typedef __attribute__((ext_vector_type(8))) short bf16x8;

__device__ __forceinline__ u16 f2bf(float f) {
  union { float f; u32 u; } x; x.f = f;
  u32 r = x.u + 0x7fffu + ((x.u >> 16) & 1u);   // round-to-nearest-even
  return (u16)(r >> 16);
}
__device__ __forceinline__ float bf2f(u16 s) {
  union { u32 u; float f; } x; x.u = ((u32)s) << 16;
  return x.f;
}

// ---------------- K0: cast w_qkv to bf16 ----------------
__global__ __launch_bounds__(256) void cast_w(const float* __restrict__ w,
                                              u16* __restrict__ o) {
  int i = (blockIdx.x * 256 + threadIdx.x) * 4;   // grid sized exactly
  f32x4 v = *(const f32x4*)(w + i);
  u16x4 u;
  u[0] = f2bf(v[0]); u[1] = f2bf(v[1]); u[2] = f2bf(v[2]); u[3] = f2bf(v[3]);
  *(u16x4*)(o + i) = u;
}

// ---------------- K1: net (b,c,n) f32 -> net_T (b,n,c) bf16 ----------------
__global__ __launch_bounds__(256) void transpose_cast(const float* __restrict__ net,
                                                      u16* __restrict__ netT) {
  __shared__ float t[64][65];
  const int b = blockIdx.z, c0 = blockIdx.y * 64, n0 = blockIdx.x * 64;
  const int tid = threadIdx.x;
  const int col4 = (tid & 15) * 4, r0 = tid >> 4;
#pragma unroll
  for (int i = 0; i < 4; ++i) {
    int r = r0 + i * 16;
    f32x4 v = *(const f32x4*)(net + (size_t)(b * 256 + c0 + r) * 4096 + n0 + col4);
    t[r][col4 + 0] = v[0]; t[r][col4 + 1] = v[1];
    t[r][col4 + 2] = v[2]; t[r][col4 + 3] = v[3];
  }
  __syncthreads();
  const int cc4 = (tid & 15) * 4, nr0 = tid >> 4;
#pragma unroll
  for (int i = 0; i < 4; ++i) {
    int nr = nr0 + i * 16;
    u16x4 u;
    u[0] = f2bf(t[cc4 + 0][nr]); u[1] = f2bf(t[cc4 + 1][nr]);
    u[2] = f2bf(t[cc4 + 2][nr]); u[3] = f2bf(t[cc4 + 3][nr]);
    *(u16x4*)(netT + (size_t)(b * 4096 + n0 + nr) * 256 + c0 + cc4) = u;
  }
}

// ---------------- K2: qkv GEMM (M=1536, K=256, N=4096) ----------------
// A = w_qkv bf16 [1536][256]; B = net_T bf16 [b][4096][256] (N,K layout)
// q (o<512)  -> q_t[b][n][o]   (transposed store, contiguous 4x bf16)
// k (512..)  -> kbuf[b][o-512][n]
// v (1024..) -> vbuf[b][o-1024][n]
__global__ __launch_bounds__(256) void gemm_qkv(const u16* __restrict__ wq,
                                                const u16* __restrict__ netT,
                                                u16* __restrict__ qt,
                                                u16* __restrict__ kbuf,
                                                u16* __restrict__ vbuf) {
  __shared__ u16 As[128 * 64];
  __shared__ u16 Bs[128 * 64];
  const int b = blockIdx.z;
  const int ot = blockIdx.y;            // 0..11 (o-tile of 128)
  const int nt = blockIdx.x;            // 0..31 (n-tile of 128)
  const int o0 = ot * 128, n0 = nt * 128;
  const int tid = threadIdx.x;
  const int lane = tid & 63, wid = tid >> 6;
  const int wr = wid >> 1, wc = wid & 1;
  const int lr = lane & 15, lg = lane >> 4;

  const u16* Aptr = wq + (size_t)o0 * 256;
  const u16* Bptr = netT + (size_t)(b * 4096 + n0) * 256;

  f32x4 acc[4][4] = {};
  u32x4 ra[4], rb[4];
#pragma unroll
  for (int i = 0; i < 4; ++i) {
    int idx = i * 2048 + tid * 8;
    int r = idx >> 6, c = idx & 63;
    ra[i] = *(const u32x4*)(Aptr + r * 256 + c);
    rb[i] = *(const u32x4*)(Bptr + r * 256 + c);
  }
  for (int ks = 0; ks < 4; ++ks) {
    __syncthreads();
#pragma unroll
    for (int i = 0; i < 4; ++i) {
      int idx = i * 2048 + tid * 8;
      *(u32x4*)(As + idx) = ra[i];
      *(u32x4*)(Bs + idx) = rb[i];
    }
    __syncthreads();
    if (ks < 3) {
      int k0 = (ks + 1) * 64;
#pragma unroll
      for (int i = 0; i < 4; ++i) {
        int idx = i * 2048 + tid * 8;
        int r = idx >> 6, c = idx & 63;
        ra[i] = *(const u32x4*)(Aptr + r * 256 + k0 + c);
        rb[i] = *(const u32x4*)(Bptr + r * 256 + k0 + c);
      }
    }
#pragma unroll
    for (int kk = 0; kk < 2; ++kk) {
      bf16x8 af[4], bfr[4];
#pragma unroll
      for (int mi = 0; mi < 4; ++mi)
        af[mi] = *(const bf16x8*)(As + (wr * 64 + mi * 16 + lr) * 64 + kk * 32 + lg * 8);
#pragma unroll
      for (int ni = 0; ni < 4; ++ni)
        bfr[ni] = *(const bf16x8*)(Bs + (wc * 64 + ni * 16 + lr) * 64 + kk * 32 + lg * 8);
#pragma unroll
      for (int mi = 0; mi < 4; ++mi)
#pragma unroll
        for (int ni = 0; ni < 4; ++ni)
          acc[mi][ni] = __builtin_amdgcn_mfma_f32_16x16x32_bf16(af[mi], bfr[ni], acc[mi][ni], 0, 0, 0);
    }
  }
  // epilogue: C elem (o = obase + mi*16 + lg*4 + j, n = nbase + ni*16 + lr)
  const int obase = o0 + wr * 64;
  const int nbase = n0 + wc * 64;
  if (ot < 4) {                    // q -> transposed store q_t[b][n][o]
#pragma unroll
    for (int mi = 0; mi < 4; ++mi)
#pragma unroll
      for (int ni = 0; ni < 4; ++ni) {
        int o = obase + mi * 16 + lg * 4;
        int n = nbase + ni * 16 + lr;
        u16x4 u;
        u[0] = f2bf(acc[mi][ni][0]); u[1] = f2bf(acc[mi][ni][1]);
        u[2] = f2bf(acc[mi][ni][2]); u[3] = f2bf(acc[mi][ni][3]);
        *(u16x4*)(qt + (size_t)(b * 4096 + n) * 512 + o) = u;
      }
  } else {
    u16* dst = (ot < 8) ? kbuf : vbuf;
    const int osub = obase - ((ot < 8) ? 512 : 1024);
#pragma unroll
    for (int mi = 0; mi < 4; ++mi)
#pragma unroll
      for (int ni = 0; ni < 4; ++ni) {
        int r = osub + mi * 16 + lg * 4;
        int n = nbase + ni * 16 + lr;
#pragma unroll
        for (int j = 0; j < 4; ++j)
          dst[(size_t)(b * 512 + r + j) * 4096 + n] = f2bf(acc[mi][ni][j]);
      }
  }
}

// ---------------- K3: context = softmax(k) @ v^T per (b,h) ----------------
__global__ __launch_bounds__(256) void ctx_kernel(const u16* __restrict__ kbuf,
                                                  const u16* __restrict__ vbuf,
                                                  float* __restrict__ ctx) {
  __shared__ float cpart[4][64][64];   // 64 KB
  __shared__ float spart[4][64];
  const int bh = blockIdx.x;           // b*8 + h
  const u16* kp = kbuf + (size_t)bh * 64 * 4096;
  const u16* vp = vbuf + (size_t)bh * 64 * 4096;
  const int tid = threadIdx.x, lane = tid & 63, wid = tid >> 6;
  const int lr = lane & 15, lg = lane >> 4;

  f32x4 acc[4][4] = {};
  float sacc[4] = {0.f, 0.f, 0.f, 0.f};

  for (int it = 0; it < 32; ++it) {
    const int n0 = wid * 1024 + it * 32 + lg * 8;
    bf16x8 af[4], bv[4];
#pragma unroll
    for (int mi = 0; mi < 4; ++mi) {
      u32x4 kv = *(const u32x4*)(kp + (size_t)(mi * 16 + lr) * 4096 + n0);
      const u16* us = (const u16*)&kv;
      bf16x8 a;
      float s = 0.f;
#pragma unroll
      for (int j = 0; j < 8; ++j) {
        float e = __expf(bf2f(us[j]));
        s += e;
        ((u16*)&a)[j] = f2bf(e);
      }
      sacc[mi] += s;
      af[mi] = a;
    }
#pragma unroll
    for (int ni = 0; ni < 4; ++ni)
      bv[ni] = *(const bf16x8*)(vp + (size_t)(ni * 16 + lr) * 4096 + n0);
#pragma unroll
    for (int mi = 0; mi < 4; ++mi)
#pragma unroll
      for (int ni = 0; ni < 4; ++ni)
        acc[mi][ni] = __builtin_amdgcn_mfma_f32_16x16x32_bf16(af[mi], bv[ni], acc[mi][ni], 0, 0, 0);
  }

#pragma unroll
  for (int mi = 0; mi < 4; ++mi) {
#pragma unroll
    for (int ni = 0; ni < 4; ++ni)
#pragma unroll
      for (int j = 0; j < 4; ++j)
        cpart[wid][mi * 16 + lg * 4 + j][ni * 16 + lr] = acc[mi][ni][j];
    float s = sacc[mi];
    s += __shfl_xor(s, 16);
    s += __shfl_xor(s, 32);
    if (lg == 0) spart[wid][mi * 16 + lr] = s;
  }
  __syncthreads();
#pragma unroll
  for (int i = 0; i < 16; ++i) {
    int f = tid + i * 256;
    int d = f >> 6, e = f & 63;
    float v = cpart[0][d][e] + cpart[1][d][e] + cpart[2][d][e] + cpart[3][d][e];
    float s = spart[0][d] + spart[1][d] + spart[2][d] + spart[3][d];
    ctx[(size_t)bh * 4096 + f] = v / s;
  }
}

// ---------------- K4: W2[b][c][h*64+d] = sum_e w_out[c][h*64+e]*ctx[bh][d][e] ----------------
__global__ __launch_bounds__(256) void fold_w2(const float* __restrict__ ctx,
                                               const float* __restrict__ wout,
                                               u16* __restrict__ W2) {
  __shared__ float cl[16 * 64];
  const int bh = blockIdx.x, dq = blockIdx.y;
  const int b = bh >> 3, h = bh & 7;
  const int tid = threadIdx.x;
  *(f32x4*)&cl[tid * 4] = *(const f32x4*)(ctx + (size_t)bh * 4096 + dq * 1024 + tid * 4);
  __syncthreads();
  const int c = tid;
  f32x4 wv[16];
  const float* wrow = wout + (size_t)c * 512 + h * 64;
#pragma unroll
  for (int i = 0; i < 16; ++i) wv[i] = *(const f32x4*)(wrow + i * 4);
#pragma unroll
  for (int d = 0; d < 16; ++d) {
    f32x4 s4 = {0.f, 0.f, 0.f, 0.f};
#pragma unroll
    for (int e4 = 0; e4 < 16; ++e4) {
      f32x4 cv = *(const f32x4*)&cl[d * 64 + e4 * 4];
      s4 += wv[e4] * cv;
    }
    float s = s4[0] + s4[1] + s4[2] + s4[3];
    W2[(size_t)(b * 256 + c) * 512 + h * 64 + dq * 16 + d] = f2bf(s);
  }
}

// ---------------- K5: out = W2 @ q_t^T + b_out (M=256, K=512, N=4096) ----------------
__global__ __launch_bounds__(256) void gemm_out(const u16* __restrict__ W2,
                                                const u16* __restrict__ qt,
                                                const float* __restrict__ bout,
                                                float* __restrict__ out) {
  __shared__ u16 As[128 * 64];
  __shared__ u16 Bs[128 * 64];
  const int b = blockIdx.z;
  const int ct = blockIdx.y;            // 0..1
  const int nt = blockIdx.x;            // 0..31
  const int c0 = ct * 128, n0 = nt * 128;
  const int tid = threadIdx.x;
  const int lane = tid & 63, wid = tid >> 6;
  const int wr = wid >> 1, wc = wid & 1;
  const int lr = lane & 15, lg = lane >> 4;

  const u16* Aptr = W2 + (size_t)b * 256 * 512 + (size_t)c0 * 512;
  const u16* Bptr = qt + (size_t)(b * 4096 + n0) * 512;

  f32x4 acc[4][4] = {};
  u32x4 ra[4], rb[4];
#pragma unroll
  for (int i = 0; i < 4; ++i) {
    int idx = i * 2048 + tid * 8;
    int r = idx >> 6, c = idx & 63;
    ra[i] = *(const u32x4*)(Aptr + r * 512 + c);
    rb[i] = *(const u32x4*)(Bptr + r * 512 + c);
  }
  for (int ks = 0; ks < 8; ++ks) {
    __syncthreads();
#pragma unroll
    for (int i = 0; i < 4; ++i) {
      int idx = i * 2048 + tid * 8;
      *(u32x4*)(As + idx) = ra[i];
      *(u32x4*)(Bs + idx) = rb[i];
    }
    __syncthreads();
    if (ks < 7) {
      int k0 = (ks + 1) * 64;
#pragma unroll
      for (int i = 0; i < 4; ++i) {
        int idx = i * 2048 + tid * 8;
        int r = idx >> 6, c = idx & 63;
        ra[i] = *(const u32x4*)(Aptr + r * 512 + k0 + c);
        rb[i] = *(const u32x4*)(Bptr + r * 512 + k0 + c);
      }
    }
#pragma unroll
    for (int kk = 0; kk < 2; ++kk) {
      bf16x8 af[4], bfr[4];
#pragma unroll
      for (int mi = 0; mi < 4; ++mi)
        af[mi] = *(const bf16x8*)(As + (wr * 64 + mi * 16 + lr) * 64 + kk * 32 + lg * 8);
#pragma unroll
      for (int ni = 0; ni < 4; ++ni)
        bfr[ni] = *(const bf16x8*)(Bs + (wc * 64 + ni * 16 + lr) * 64 + kk * 32 + lg * 8);
#pragma unroll
      for (int mi = 0; mi < 4; ++mi)
#pragma unroll
        for (int ni = 0; ni < 4; ++ni)
          acc[mi][ni] = __builtin_amdgcn_mfma_f32_16x16x32_bf16(af[mi], bfr[ni], acc[mi][ni], 0, 0, 0);
    }
  }
  const int cbase = c0 + wr * 64;
  const int nbase = n0 + wc * 64;
#pragma unroll
  for (int mi = 0; mi < 4; ++mi)
#pragma unroll
    for (int ni = 0; ni < 4; ++ni) {
      int c = cbase + mi * 16 + lg * 4;
      int n = nbase + ni * 16 + lr;
#pragma unroll
      for (int j = 0; j < 4; ++j)
        out[(size_t)(b * 256 + c + j) * 4096 + n] = acc[mi][ni][j] + bout[c + j];
    }
}

// ---------------------------------------------------------------------------
extern "C" void kernel_launch(void* const* d_in, const int* in_sizes, int n_in,
                              void* d_out, int out_size, void* d_ws, size_t ws_size,
                              hipStream_t stream) {
  const float* net  = (const float*)d_in[0];   // [16][256][4096]
  const float* wqkv = (const float*)d_in[1];   // [1536][256]
  const float* wout = (const float*)d_in[2];   // [256][512]
  const float* bout = (const float*)d_in[3];   // [256]
  float* out = (float*)d_out;

  char* ws = (char*)d_ws;
  u16*   qt   = (u16*)(ws + 0);
  u16*   kbuf = (u16*)(ws + 67108864);
  u16*   vbuf = (u16*)(ws + 134217728);
  float* ctx  = (float*)(ws + 201326592);
  u16*   W2   = (u16*)(ws + 203423744);
  u16*   wqb  = (u16*)(ws + 207618048);
  u16*   netT = (u16*)d_out;   // scratch: 33.5MB of the 67MB output, dead before K5

  cast_w<<<384, 256, 0, stream>>>(wqkv, wqb);
  transpose_cast<<<dim3(64, 4, 16), 256, 0, stream>>>(net, netT);
  gemm_qkv<<<dim3(32, 12, 16), 256, 0, stream>>>(wqb, netT, qt, kbuf, vbuf);
  ctx_kernel<<<128, 256, 0, stream>>>(kbuf, vbuf, ctx);
  fold_w2<<<dim3(128, 4), 256, 0, stream>>>(ctx, wout, W2);
  gemm_out<<<dim3(32, 2, 16), 256, 0, stream>>>(W2, qt, bout, out);
}

// Round 2
// 169.456 us; speedup vs baseline: 1.4245x; 1.4245x over previous
//
#include <hip/hip_runtime.h>

// ---------------------------------------------------------------------------
// LinearDepthWiseAttention, algebraically folded:
//   kv   = w_qkv[512:1536] @ net          (per b; k rows 0..511, v rows 512..1023)
//   ek   = exp(k)  (no max-sub: |k|<~6)   ; stored bf16
//   ctx[b,h] = (ek_h @ v_h^T),  sums via ones-row MFMA, both per n-chunk partials
//   W2[b,c,h*64+d] = sum_e w_out[c,h*64+e] * ctx[b,h,d,e]/sum[b,h,d]
//   W3[b] = W2[b] @ w_q^T-layout          (q NEVER materialized)
//   out[b] = W3[b] @ net[b] + b_out
// Kernels:
//   cast_w          : w_qkv rows 512..1535 f32 -> bf16 (wqb_kv)
//   transpose_cast_g: generic [R][C] f32 -> [C][R] bf16 (netT, wqTb)
//   gemm128<LD,NK,MODE>: 128x128x64 bf16 MFMA GEMM, global_load_lds(16B) dbuf
//       MODE 0: kv  (exp on k-half, LDS-staged coalesced bf16 stores)
//       MODE 2: W3  (LDS-staged bf16 store)
//       MODE 1: out (f32 + bias, LDS-staged f32x4 store)
//   ctx_partial     : per (bh, chunk of 512 n): ek@v^T + ek@ones partials
//   fold_w2         : reduce 8 partials, normalize, fold with w_out -> W2 bf16
// Workspace (bytes):
//   netT  [16][4096][256] bf16 @ 0           (33554432)
//   ek    [16][512][4096]  bf16 @ 33554432   (67108864)
//   vv    [16][512][4096]  bf16 @ 100663296  (67108864)
//   ctxp  [128][8][64][64] f32  @ 167772160  (16777216)
//   sump  [128][8][64]     f32  @ 184549376  (131072)
//   W2    [16][256][512]   bf16 @ 184680448  (4194304)
//   W3    [16][256][256]   bf16 @ 188874752  (2097152)
//   wqb_kv[1024][256]      bf16 @ 190971904  (524288)
//   wqTb  [256][512]       bf16 @ 191496192  (262144)   total ~191.8 MB
// ---------------------------------------------------------------------------

typedef unsigned short u16;
typedef unsigned int u32;
typedef __attribute__((ext_vector_type(4))) u16 u16x4;
typedef __attribute__((ext_vector_type(4))) u32 u32x4;
typedef __attribute__((ext_vector_type(4))) float f32x4;
typedef __attribute__((ext_vector_type(8))) short bf16x8;

__device__ __forceinline__ u16 f2bf(float f) {
  union { float f; u32 u; } x; x.f = f;
  u32 r = x.u + 0x7fffu + ((x.u >> 16) & 1u);   // round-to-nearest-even
  return (u16)(r >> 16);
}
__device__ __forceinline__ float bf2f(u16 s) {
  union { u32 u; float f; } x; x.u = ((u32)s) << 16;
  return x.f;
}

// async global->LDS, 16B per lane; LDS dest must be wave-uniform base.
__device__ __forceinline__ void async16(const u16* g, u16* l) {
  __builtin_amdgcn_global_load_lds(
      (const __attribute__((address_space(1))) void*)g,
      (__attribute__((address_space(3))) void*)l, 16, 0, 0);
}

// ---------------- cast w_qkv[512:1536] to bf16 ----------------
__global__ __launch_bounds__(256) void cast_w(const float* __restrict__ w,
                                              u16* __restrict__ o) {
  int i = (blockIdx.x * 256 + threadIdx.x) * 4;
  f32x4 v = *(const f32x4*)(w + i);
  u16x4 u;
  u[0] = f2bf(v[0]); u[1] = f2bf(v[1]); u[2] = f2bf(v[2]); u[3] = f2bf(v[3]);
  *(u16x4*)(o + i) = u;
}

// ---------------- generic transpose+cast: in[b][R][C] f32 -> out[b][C][R] bf16 ----
__global__ __launch_bounds__(256) void transpose_cast_g(const float* __restrict__ in,
                                                        u16* __restrict__ out,
                                                        int R, int C) {
  __shared__ float t[64][65];
  const int b = blockIdx.z, r0 = blockIdx.y * 64, c0 = blockIdx.x * 64;
  const float* ip = in + (size_t)b * R * C;
  u16* op = out + (size_t)b * R * C;
  const int tid = threadIdx.x;
  const int col4 = (tid & 15) * 4, rr0 = tid >> 4;
#pragma unroll
  for (int i = 0; i < 4; ++i) {
    int r = rr0 + i * 16;
    f32x4 v = *(const f32x4*)(ip + (size_t)(r0 + r) * C + c0 + col4);
    t[r][col4 + 0] = v[0]; t[r][col4 + 1] = v[1];
    t[r][col4 + 2] = v[2]; t[r][col4 + 3] = v[3];
  }
  __syncthreads();
  const int cc4 = (tid & 15) * 4, nr0 = tid >> 4;
#pragma unroll
  for (int i = 0; i < 4; ++i) {
    int nr = nr0 + i * 16;
    u16x4 u;
    u[0] = f2bf(t[cc4 + 0][nr]); u[1] = f2bf(t[cc4 + 1][nr]);
    u[2] = f2bf(t[cc4 + 2][nr]); u[3] = f2bf(t[cc4 + 3][nr]);
    *(u16x4*)(op + (size_t)(c0 + nr) * R + r0 + cc4) = u;
  }
}

// ---------------- gemm128: C[128x128] = A[128xK] * B[128xK]^T, bf16 MFMA ------
// A,B row-major with leading dim LD (K-contiguous). NK = K/64 steps.
// MODE 0: kv epilogue (mt<4 -> exp -> O0=ek, else O1=vv), bf16 LDS-staged.
// MODE 1: f32 out + bias, LDS-staged.  MODE 2: bf16 plain (W3), LDS-staged.
template <int LD, int NK, int MODE>
__global__ __launch_bounds__(256) void gemm128(const u16* __restrict__ A,
                                               const u16* __restrict__ B,
                                               size_t aStride, size_t bStride,
                                               void* __restrict__ O0,
                                               void* __restrict__ O1,
                                               const float* __restrict__ bias) {
  __shared__ __align__(16) u16 SM[32768];   // As[2][8192] ++ Bs[2][8192] = 64KB
  const int b = blockIdx.z, mt = blockIdx.y, nt = blockIdx.x;
  const int tid = threadIdx.x, lane = tid & 63, wid = tid >> 6;
  const int wr = wid >> 1, wc = wid & 1, lr = lane & 15, lg = lane >> 4;
  const u16* Ap = A + (size_t)b * aStride + (size_t)mt * 128 * LD;
  const u16* Bp = B + (size_t)b * bStride + (size_t)nt * 128 * LD;

  auto stage = [&](int buf, int ks) {
    const int k0 = ks * 64;
#pragma unroll
    for (int i = 0; i < 4; ++i) {
      const int idx = i * 2048 + tid * 8;
      const int r = idx >> 6, c = idx & 63;
      async16(Ap + (size_t)r * LD + k0 + c, SM + buf * 8192 + i * 2048 + wid * 512);
      async16(Bp + (size_t)r * LD + k0 + c, SM + 16384 + buf * 8192 + i * 2048 + wid * 512);
    }
  };

  f32x4 acc[4][4] = {};
  stage(0, 0);
  asm volatile("s_waitcnt vmcnt(0)" ::: "memory");
  __syncthreads();
  for (int ks = 0; ks < NK; ++ks) {
    const int buf = ks & 1;
    if (ks + 1 < NK) stage(buf ^ 1, ks + 1);
    const u16* Ab = SM + buf * 8192;
    const u16* Bb = SM + 16384 + buf * 8192;
#pragma unroll
    for (int kk = 0; kk < 2; ++kk) {
      bf16x8 af[4], bfr[4];
#pragma unroll
      for (int mi = 0; mi < 4; ++mi)
        af[mi] = *(const bf16x8*)(Ab + (wr * 64 + mi * 16 + lr) * 64 + kk * 32 + lg * 8);
#pragma unroll
      for (int ni = 0; ni < 4; ++ni)
        bfr[ni] = *(const bf16x8*)(Bb + (wc * 64 + ni * 16 + lr) * 64 + kk * 32 + lg * 8);
#pragma unroll
      for (int mi = 0; mi < 4; ++mi)
#pragma unroll
        for (int ni = 0; ni < 4; ++ni)
          acc[mi][ni] = __builtin_amdgcn_mfma_f32_16x16x32_bf16(af[mi], bfr[ni], acc[mi][ni], 0, 0, 0);
    }
    asm volatile("s_waitcnt vmcnt(0)" ::: "memory");
    __syncthreads();
  }

  // ---- epilogue (LDS re-staged for coalesced stores) ----
  if constexpr (MODE == 0 || MODE == 2) {
    u16* Cs = SM;                         // 32KB: 128x128 u16
    const bool isK = (MODE == 0) && (mt < 4);
#pragma unroll
    for (int mi = 0; mi < 4; ++mi)
#pragma unroll
      for (int ni = 0; ni < 4; ++ni)
#pragma unroll
        for (int j = 0; j < 4; ++j) {
          float v = acc[mi][ni][j];
          if (isK) v = __expf(v);
          Cs[(wr * 64 + mi * 16 + lg * 4 + j) * 128 + wc * 64 + ni * 16 + lr] = f2bf(v);
        }
    __syncthreads();
    if constexpr (MODE == 0) {
      u16* dst = (mt < 4) ? (u16*)O0 : (u16*)O1;
      const int ob = (mt & 3) * 128;
#pragma unroll
      for (int p = 0; p < 8; ++p) {
        const int idx = p * 2048 + tid * 8;
        const int r = idx >> 7, cc = idx & 127;
        *(u32x4*)(dst + ((size_t)b * 512 + ob + r) * 4096 + nt * 128 + cc) =
            *(const u32x4*)(Cs + idx);
      }
    } else {
      u16* dst = (u16*)O0;                // W3 [256][256]
#pragma unroll
      for (int p = 0; p < 8; ++p) {
        const int idx = p * 2048 + tid * 8;
        const int r = idx >> 7, cc = idx & 127;
        *(u32x4*)(dst + ((size_t)b * 256 + mt * 128 + r) * 256 + nt * 128 + cc) =
            *(const u32x4*)(Cs + idx);
      }
    }
  } else {                                // MODE 1: f32 + bias
    float* Cf = (float*)SM;               // 64KB: 128x128 f32
#pragma unroll
    for (int mi = 0; mi < 4; ++mi)
#pragma unroll
      for (int ni = 0; ni < 4; ++ni)
#pragma unroll
        for (int j = 0; j < 4; ++j) {
          const int row = wr * 64 + mi * 16 + lg * 4 + j;
          Cf[row * 128 + wc * 64 + ni * 16 + lr] = acc[mi][ni][j] + bias[mt * 128 + row];
        }
    __syncthreads();
    float* op = (float*)O0;
#pragma unroll
    for (int p = 0; p < 16; ++p) {
      const int idx = p * 1024 + tid * 4;
      const int r = idx >> 7, cc = idx & 127;
      *(f32x4*)(op + ((size_t)b * 256 + mt * 128 + r) * 4096 + nt * 128 + cc) =
          *(const f32x4*)(Cf + idx);
    }
  }
}

// ---------------- ctx partials: per (bh, chunk of 512 n) ----------------
// acc = ek @ v^T (64x64), accs = ek @ ones (rowsums), both f32 partials.
__global__ __launch_bounds__(256) void ctx_partial(const u16* __restrict__ ek,
                                                   const u16* __restrict__ vv,
                                                   float* __restrict__ ctxp,
                                                   float* __restrict__ sump) {
  __shared__ float cpart[4][64][64];   // 64 KB
  __shared__ float spart[4][64];
  const int bh = blockIdx.x, ch = blockIdx.y;
  const u16* kp = ek + (size_t)bh * 64 * 4096;
  const u16* vp = vv + (size_t)bh * 64 * 4096;
  const int tid = threadIdx.x, lane = tid & 63, wid = tid >> 6;
  const int lr = lane & 15, lg = lane >> 4;

  f32x4 acc[4][4] = {};
  f32x4 accs[4] = {};
  bf16x8 onef = {};
  if (lr == 0) {
#pragma unroll
    for (int j = 0; j < 8; ++j) ((u16*)&onef)[j] = 0x3F80;  // bf16 1.0
  }

  for (int it = 0; it < 4; ++it) {
    const int n0 = ch * 512 + wid * 128 + it * 32 + lg * 8;
    bf16x8 af[4], bv[4];
#pragma unroll
    for (int mi = 0; mi < 4; ++mi)
      af[mi] = *(const bf16x8*)(kp + (size_t)(mi * 16 + lr) * 4096 + n0);
#pragma unroll
    for (int ni = 0; ni < 4; ++ni)
      bv[ni] = *(const bf16x8*)(vp + (size_t)(ni * 16 + lr) * 4096 + n0);
#pragma unroll
    for (int mi = 0; mi < 4; ++mi) {
#pragma unroll
      for (int ni = 0; ni < 4; ++ni)
        acc[mi][ni] = __builtin_amdgcn_mfma_f32_16x16x32_bf16(af[mi], bv[ni], acc[mi][ni], 0, 0, 0);
      accs[mi] = __builtin_amdgcn_mfma_f32_16x16x32_bf16(af[mi], onef, accs[mi], 0, 0, 0);
    }
  }

#pragma unroll
  for (int mi = 0; mi < 4; ++mi) {
#pragma unroll
    for (int ni = 0; ni < 4; ++ni)
#pragma unroll
      for (int j = 0; j < 4; ++j)
        cpart[wid][mi * 16 + lg * 4 + j][ni * 16 + lr] = acc[mi][ni][j];
    if (lr == 0) {
#pragma unroll
      for (int j = 0; j < 4; ++j) spart[wid][mi * 16 + lg * 4 + j] = accs[mi][j];
    }
  }
  __syncthreads();
  float* cp = ctxp + ((size_t)bh * 8 + ch) * 4096;
#pragma unroll
  for (int i = 0; i < 16; ++i) {
    const int f = tid + i * 256;
    const int d = f >> 6, e = f & 63;
    cp[f] = cpart[0][d][e] + cpart[1][d][e] + cpart[2][d][e] + cpart[3][d][e];
  }
  if (tid < 64)
    sump[((size_t)bh * 8 + ch) * 64 + tid] =
        spart[0][tid] + spart[1][tid] + spart[2][tid] + spart[3][tid];
}

// ---------------- fold_w2: W2[b][c][h*64+d] = sum_e wout[c][h*64+e]*ctx/s ----
__global__ __launch_bounds__(256) void fold_w2(const float* __restrict__ ctxp,
                                               const float* __restrict__ sump,
                                               const float* __restrict__ wout,
                                               u16* __restrict__ W2) {
  __shared__ float cl[16 * 64];
  __shared__ float sl[16];
  const int bh = blockIdx.x, dq = blockIdx.y;
  const int b = bh >> 3, h = bh & 7;
  const int tid = threadIdx.x;
  f32x4 v4 = {0.f, 0.f, 0.f, 0.f};
#pragma unroll
  for (int ch = 0; ch < 8; ++ch)
    v4 += *(const f32x4*)(ctxp + ((size_t)bh * 8 + ch) * 4096 + dq * 1024 + tid * 4);
  *(f32x4*)&cl[tid * 4] = v4;
  if (tid < 16) {
    float s = 0.f;
#pragma unroll
    for (int ch = 0; ch < 8; ++ch)
      s += sump[((size_t)bh * 8 + ch) * 64 + dq * 16 + tid];
    sl[tid] = s;
  }
  __syncthreads();
  const int c = tid;
  f32x4 wv[16];
  const float* wrow = wout + (size_t)c * 512 + h * 64;
#pragma unroll
  for (int i = 0; i < 16; ++i) wv[i] = *(const f32x4*)(wrow + i * 4);
#pragma unroll
  for (int d = 0; d < 16; ++d) {
    f32x4 s4 = {0.f, 0.f, 0.f, 0.f};
#pragma unroll
    for (int e4 = 0; e4 < 16; ++e4) {
      f32x4 cv = *(const f32x4*)&cl[d * 64 + e4 * 4];
      s4 += wv[e4] * cv;
    }
    const float s = (s4[0] + s4[1] + s4[2] + s4[3]) / sl[d];
    W2[((size_t)b * 256 + c) * 512 + h * 64 + dq * 16 + d] = f2bf(s);
  }
}

// ---------------------------------------------------------------------------
extern "C" void kernel_launch(void* const* d_in, const int* in_sizes, int n_in,
                              void* d_out, int out_size, void* d_ws, size_t ws_size,
                              hipStream_t stream) {
  const float* net  = (const float*)d_in[0];   // [16][256][4096]
  const float* wqkv = (const float*)d_in[1];   // [1536][256]
  const float* wout = (const float*)d_in[2];   // [256][512]
  const float* bout = (const float*)d_in[3];   // [256]
  float* out = (float*)d_out;

  char* ws = (char*)d_ws;
  u16*   netT = (u16*)(ws + 0);
  u16*   ek   = (u16*)(ws + 33554432);
  u16*   vv   = (u16*)(ws + 100663296);
  float* ctxp = (float*)(ws + 167772160);
  float* sump = (float*)(ws + 184549376);
  u16*   W2   = (u16*)(ws + 184680448);
  u16*   W3   = (u16*)(ws + 188874752);
  u16*   wqkv_kv = (u16*)(ws + 190971904);
  u16*   wqTb = (u16*)(ws + 191496192);

  // w_kv (rows 512..1535) -> bf16
  cast_w<<<256, 256, 0, stream>>>(wqkv + 512 * 256, wqkv_kv);
  // net (b,c,n) -> netT (b,n,c) bf16
  transpose_cast_g<<<dim3(64, 4, 16), 256, 0, stream>>>(net, netT, 256, 4096);
  // w_q (rows 0..511) [512][256] -> wqTb [256][512] bf16
  transpose_cast_g<<<dim3(4, 8, 1), 256, 0, stream>>>(wqkv, wqTb, 512, 256);
  // kv GEMM: M=1024 K=256 N=4096, exp on k-half
  gemm128<256, 4, 0><<<dim3(32, 8, 16), 256, 0, stream>>>(
      wqkv_kv, netT, 0, (size_t)4096 * 256, ek, vv, nullptr);
  // ctx partials over 8 n-chunks
  ctx_partial<<<dim3(128, 8), 256, 0, stream>>>(ek, vv, ctxp, sump);
  // reduce + normalize + fold with w_out
  fold_w2<<<dim3(128, 4), 256, 0, stream>>>(ctxp, sump, wout, W2);
  // W3[b] = W2[b] @ wqT : M=256 K=512 N=256
  gemm128<512, 8, 2><<<dim3(2, 2, 16), 256, 0, stream>>>(
      W2, wqTb, (size_t)256 * 512, 0, W3, nullptr, nullptr);
  // out = W3 @ netT^T + b_out : M=256 K=256 N=4096
  gemm128<256, 4, 1><<<dim3(32, 2, 16), 256, 0, stream>>>(
      W3, netT, (size_t)256 * 256, (size_t)4096 * 256, out, nullptr, bout);
}